// Round 12
// baseline (426.440 us; speedup 1.0000x reference)
//
#include <hip/hip_runtime.h>
#include <hip/hip_bf16.h>

#define NN 4096
#define NH 8
#define TOT 208
#define NPROJ 1664

typedef __attribute__((ext_vector_type(8))) short short8;
typedef __attribute__((ext_vector_type(4))) short short4_t;
typedef __attribute__((ext_vector_type(4))) float float4_t;

#define MFMA __builtin_amdgcn_mfma_f32_16x16x32_bf16

__device__ __forceinline__ short f2bf(float f){
  union { float f; unsigned u; } v; v.f = f;
  unsigned r = v.u + 0x7fffu + ((v.u >> 16) & 1u);
  return (short)(r >> 16);
}

__device__ __forceinline__ float bitsf(unsigned u){
  union { unsigned u; float f; } v; v.u = u; return v.f;
}

// barrier without vmcnt drain: LDS visibility needs lgkmcnt(0) only.
#define BAR() do{ \
    asm volatile("s_waitcnt lgkmcnt(0)" ::: "memory"); \
    __builtin_amdgcn_s_barrier(); \
    asm volatile("" ::: "memory"); \
  }while(0)

// ---------------- elementwise f32 -> bf16 (x4 per thread) ----------------
__global__ void k_cvt(const float* __restrict__ in, short* __restrict__ out, int n4){
  int i = blockIdx.x*256 + threadIdx.x;
  if(i >= n4) return;
  float4_t v = *(const float4_t*)(in + (size_t)i*4);
  short4_t o;
  o[0]=f2bf(v[0]); o[1]=f2bf(v[1]); o[2]=f2bf(v[2]); o[3]=f2bf(v[3]);
  *(short4_t*)(out + (size_t)i*4) = o;
}

// ---------------- transpose + cvt: out[c][r] = bf16(in[r][c]) ----------------
__global__ void k_trans(const float* __restrict__ in, short* __restrict__ out, int R, int C){
  __shared__ float tile[32][33];
  int bc = blockIdx.x*32, br = blockIdx.y*32;
  int tx = threadIdx.x, ty = threadIdx.y;
  #pragma unroll
  for(int dy=0; dy<32; dy+=8){
    int r = br+ty+dy, c = bc+tx;
    if(r<R && c<C) tile[ty+dy][tx] = in[(size_t)r*C + c];
  }
  __syncthreads();
  #pragma unroll
  for(int dy=0; dy<32; dy+=8){
    int c = bc+ty+dy, r = br+tx;
    if(c<C && r<R) out[(size_t)c*R + r] = f2bf(tile[tx][ty+dy]);
  }
}

// ---------------- generic bf16 GEMM: C[M][Ncols] f32 = A[M][K] * Bt[Ncols][K]^T ----------------
__global__ __launch_bounds__(256) void k_gemm(
    const short* __restrict__ A, const short* __restrict__ Bt, float* __restrict__ C,
    int M, int Ncols, int K)
{
  __shared__ __align__(16) short As[2][2048];
  __shared__ __align__(16) short Bs[2][2048];
  const int tid = threadIdx.x;
  const int l = tid & 63, w = tid >> 6;
  const int wm = w >> 1, wn = w & 1;
  const int g = l >> 4, i16 = l & 15;
  const size_t bm = (size_t)blockIdx.x * 64, bn = (size_t)blockIdx.y * 64;
  const int r = tid >> 2, cb = tid & 3;
  const int dst = r*32 + ((cb ^ (r&3))*8);
  const short* Ag = A + (bm + (size_t)r)*K + cb*8;
  const short* Bg = Bt + (bn + (size_t)r)*K + cb*8;
  float4_t z4 = {0.f,0.f,0.f,0.f};
  float4_t acc00=z4, acc01=z4, acc10=z4, acc11=z4;
  short8 ta = *(const short8*)(Ag);
  short8 tb = *(const short8*)(Bg);
  *(short8*)&As[0][dst] = ta;
  *(short8*)&Bs[0][dst] = tb;
  const int nk = K >> 5;
  int c = 0;
  const int swa = (g ^ (i16&3))*8;
  for(int kt=0; kt<nk; kt++){
    __syncthreads();
    if(kt+1 < nk){
      ta = *(const short8*)(Ag + (kt+1)*32);
      tb = *(const short8*)(Bg + (kt+1)*32);
    }
    short8 a0 = *(const short8*)&As[c][(wm*32 + i16)*32 + swa];
    short8 a1 = *(const short8*)&As[c][(wm*32 + 16 + i16)*32 + swa];
    short8 b0 = *(const short8*)&Bs[c][(wn*32 + i16)*32 + swa];
    short8 b1 = *(const short8*)&Bs[c][(wn*32 + 16 + i16)*32 + swa];
    acc00 = MFMA(a0,b0,acc00,0,0,0); acc01 = MFMA(a0,b1,acc01,0,0,0);
    acc10 = MFMA(a1,b0,acc10,0,0,0); acc11 = MFMA(a1,b1,acc11,0,0,0);
    if(kt+1 < nk){
      *(short8*)&As[c^1][dst] = ta;
      *(short8*)&Bs[c^1][dst] = tb;
    }
    c ^= 1;
  }
  #pragma unroll
  for(int rr=0; rr<4; rr++){
    C[(bm + wm*32 +      4*g + rr)*(size_t)Ncols + bn + wn*32 + i16]      = acc00[rr];
    C[(bm + wm*32 +      4*g + rr)*(size_t)Ncols + bn + wn*32 + 16 + i16] = acc01[rr];
    C[(bm + wm*32 + 16 + 4*g + rr)*(size_t)Ncols + bn + wn*32 + i16]      = acc10[rr];
    C[(bm + wm*32 + 16 + 4*g + rr)*(size_t)Ncols + bn + wn*32 + 16 + i16] = acc11[rr];
  }
}

// ---------------- pack H2 -> Qp/Kp/Vp/Rp fragment layouts ----------------
__global__ void k_pack(const float* __restrict__ H2, short* __restrict__ Qp,
                       short* __restrict__ Kp, short* __restrict__ Vp, short* __restrict__ Rp){
  int T = blockIdx.x*256 + threadIdx.x;
  if(T < 262144){
    int l = T & 63; int rest = T >> 6;
    int kb = rest & 1; rest >>= 1;
    int it = rest & 255; int h = rest >> 8;
    int i = it*16 + (l & 15);
    int col = h*TOT + kb*32 + 8*(l>>4);
    const float* s = H2 + (size_t)i*NPROJ + col;
    short8 v;
    #pragma unroll
    for(int e=0;e<8;e++) v[e] = f2bf(s[e]);
    *(short8*)(Qp + (size_t)T*8) = v;
  } else if(T < 524288){
    int T2 = T - 262144;
    int l = T2 & 63; int rest = T2 >> 6;
    int kb = rest & 1; rest >>= 1;
    int it = rest & 255; int h = rest >> 8;
    int i = it*16 + (l & 15);
    int col = h*TOT + 64 + kb*32 + 8*(l>>4);
    const float* s = H2 + (size_t)i*NPROJ + col;
    short8 v;
    #pragma unroll
    for(int e=0;e<8;e++) v[e] = f2bf(s[e]);
    *(short8*)(Kp + (size_t)T2*8) = v;
  } else if(T < 786432){
    int T2 = T - 524288;
    int l = T2 & 63; int rest = T2 >> 6;
    int db = rest & 3; rest >>= 2;
    int jt = rest & 127; int h = rest >> 7;
    int col = h*TOT + 128 + db*16 + (l & 15);
    int j0 = jt*32 + 8*(l>>4);
    short8 v;
    #pragma unroll
    for(int e=0;e<8;e++) v[e] = f2bf(H2[(size_t)(j0+e)*NPROJ + col]);
    *(short8*)(Vp + (size_t)T2*8) = v;
  } else {
    int T2 = T - 786432;
    int half = T2 & 1; int hh = (T2>>1) & 15; int i = T2 >> 5;
    short8 v;
    #pragma unroll
    for(int e=0;e<8;e++) v[e] = 0;
    if(hh < 8){
      const float* s = H2 + (size_t)i*NPROJ + hh*TOT + 192 + half*8;
      #pragma unroll
      for(int e=0;e<8;e++) v[e] = f2bf(s[e]);
    }
    *(short8*)(Rp + (size_t)T2*8) = v;
  }
}

// ---------------- fused attention, QBLK=32, j-halves, LDS-staged D (2-deep) ----------
// grid 256: block = (i-tile of 32 rows, j-half), 8 waves = 8 heads, 1 block/CU.
// __launch_bounds__(512, 2): only 2 waves/SIMD needed -> VGPR cap 256 (not 128),
// making the 2-deep gl staging fit WITHOUT spill (R9 spilled at cap 128).
// D staged as dense 1KB bursts -> glA/glB (2-deep, ~2 iters flight) -> bf16 ->
// double-buffered Dlds. Producer reads B-frags from LDS. kf/mi prefetch stays
// AFTER the consumer QK MFMAs (R10 ordering bug).
#define RDS2(h,j,i) (((h)*32+(j))*36+(i))
#define PS(ww,row,j) (((ww)*32+(row))*40+(j))

__global__ __launch_bounds__(512, 2) void k_attn(
    const float* __restrict__ Dm, const float* __restrict__ mask,
    const short* __restrict__ Qp, const short* __restrict__ Kp,
    const short* __restrict__ Vp, const short* __restrict__ Rp,
    float* __restrict__ Opart, float* __restrict__ lpart)
{
  __shared__ __align__(16) short Dlds[2*32*512];   // [2 buf][32 row][512] bf16 = 64KB
  __shared__ __align__(16) short rdl[18432];        // [2 buf][8 h][32 j][36 i] bf16
  __shared__ __align__(16) short p_lds[10240];      // [8 w][32 row][40 j] bf16

  const int tid = threadIdx.x;
  const int l = tid & 63, w = tid >> 6;
  const int g = l >> 4, i16 = l & 15;
  const int IT = blockIdx.x >> 1, jh = blockIdx.x & 1;
  const int i0 = IT * 32;
  const float iscale = 0.11180339887498949f;   // 1/sqrt(80)
  const float msc    = 8.944271909999159f;     // sqrt(80)

  short8 qa[4];
  #pragma unroll
  for(int rg=0; rg<2; rg++)
    #pragma unroll
    for(int kb=0; kb<2; kb++)
      qa[rg*2+kb] = *(const short8*)(Qp + (((size_t)w*256 + IT*2+rg)*2 + kb)*512 + (size_t)l*8);

  short8 ra[4];
  #pragma unroll
  for(int row=0; row<4; row++)
    #pragma unroll
    for(int e=0; e<8; e++) ra[row][e] = 0;
  if(g < 2){
    #pragma unroll
    for(int row=0; row<4; row++)
      ra[row] = *(const short8*)(Rp + (size_t)(i0+4*w+row)*256 + i16*16 + 8*g);
  }

  float4_t z4 = {0.f,0.f,0.f,0.f};
  float4_t O[4][2];
  #pragma unroll
  for(int db=0; db<4; db++){ O[db][0]=z4; O[db][1]=z4; }
  float l_r[8];
  #pragma unroll
  for(int k2=0;k2<8;k2++) l_r[k2]=0.f;

  // 2-deep D staging registers (dense 1KB bursts, all 64 lanes active)
  float4_t glA[4][2], glB[4][2];
  float mi[4][2];
  short8 kf[4], vf[4];

#define LOAD_GL(SET, ts) do{ \
    _Pragma("unroll") \
    for(int row=0; row<4; row++){ \
      const float* rb = Dm + ((size_t)(i0+4*w+row)*NN + (size_t)(ts)*32)*16; \
      SET[row][0] = *(const float4_t*)(rb + l*4); \
      SET[row][1] = *(const float4_t*)(rb + 256 + l*4); \
    } }while(0)

#define CVT_STORE(SET, bufb) do{ \
    short* dbp = Dlds + (bufb)*16384; \
    const int jw = (l>>2), r0 = 4*(l&3); \
    _Pragma("unroll") \
    for(int row=0; row<4; row++){ \
      _Pragma("unroll") \
      for(int half=0; half<2; half++){ \
        unsigned u0,u1; float4_t v = SET[row][half]; \
        asm("v_cvt_pk_bf16_f32 %0, %1, %2" : "=v"(u0) : "v"(v[0]), "v"(v[1])); \
        asm("v_cvt_pk_bf16_f32 %0, %1, %2" : "=v"(u1) : "v"(v[2]), "v"(v[3])); \
        unsigned long long pk = (unsigned long long)u0 | ((unsigned long long)u1<<32); \
        *(unsigned long long*)(dbp + (4*w+row)*512 + (half*16+jw)*16 + r0) = pk; \
      } } \
    asm volatile("" ::: "memory"); \
  }while(0)

#define LOAD_MI(tt) do{ \
    size_t jj = (size_t)(tt)*32 + i16; \
    mi[0][0] = mask[(size_t)(i0+4*w+0)*NN + jj] * msc; \
    mi[0][1] = mask[(size_t)(i0+4*w+0)*NN + jj + 16] * msc; \
    mi[1][0] = mask[(size_t)(i0+4*w+1)*NN + jj] * msc; \
    mi[1][1] = mask[(size_t)(i0+4*w+1)*NN + jj + 16] * msc; \
    mi[2][0] = mask[(size_t)(i0+4*w+2)*NN + jj] * msc; \
    mi[2][1] = mask[(size_t)(i0+4*w+2)*NN + jj + 16] * msc; \
    mi[3][0] = mask[(size_t)(i0+4*w+3)*NN + jj] * msc; \
    mi[3][1] = mask[(size_t)(i0+4*w+3)*NN + jj + 16] * msc; }while(0)

#define LOAD_K(tt) do{ \
    const short* kp = Kp + (((size_t)w*256 + (size_t)(tt)*2)*2)*512 + (size_t)l*8; \
    kf[0] = *(const short8*)(kp);        kf[1] = *(const short8*)(kp+512); \
    kf[2] = *(const short8*)(kp+1024);   kf[3] = *(const short8*)(kp+1536); }while(0)

#define LOAD_V(tt) do{ \
    const short* vp = Vp + (((size_t)w*128 + (size_t)(tt))*4)*512 + (size_t)l*8; \
    vf[0] = *(const short8*)(vp);        vf[1] = *(const short8*)(vp+512); \
    vf[2] = *(const short8*)(vp+1024);   vf[3] = *(const short8*)(vp+1536); }while(0)

// one sub-iteration: CUR = rdl/Dlds buffer of tile t; GLS holds D(t+1);
// after consuming GLS, reload it with tile TP = t+3 (clamped). TN = t+1 (clamped).
#define ATTN_ITER(CUR, GLS, TN, TP) do{ \
    const short* dcur = Dlds + (CUR)*16384; \
    short8 zf; \
    _Pragma("unroll") \
    for(int e=0;e<8;e++) zf[e] = 0; \
    _Pragma("unroll") \
    for(int row=0; row<4; row++){ \
      short8 db0 = zf, db1 = zf; \
      if(g < 2){ \
        db0 = *(const short8*)(dcur + (4*w+row)*512 + i16*16      + 8*g); \
        db1 = *(const short8*)(dcur + (4*w+row)*512 + (16+i16)*16 + 8*g); \
      } \
      float4_t c0 = {mi[row][0],mi[row][0],mi[row][0],mi[row][0]}; \
      float4_t c1 = {mi[row][1],mi[row][1],mi[row][1],mi[row][1]}; \
      c0 = MFMA(ra[row], db0, c0,0,0,0); \
      c1 = MFMA(ra[row], db1, c1,0,0,0); \
      if(g < 2){ \
        int ib = 4*w + row; \
        _Pragma("unroll") \
        for(int r=0; r<4; r++){ \
          rdl[RDS2((CUR)*8 + 4*g+r, i16,    ib)] = f2bf(c0[r]); \
          rdl[RDS2((CUR)*8 + 4*g+r, 16+i16, ib)] = f2bf(c1[r]); \
        } \
      } \
    } \
    CVT_STORE(GLS, (CUR)^1); \
    LOAD_GL(GLS, TP); \
    BAR(); \
    float4_t s[2][2]; \
    s[0][0] = MFMA(qa[0], kf[0], z4,0,0,0); s[0][0] = MFMA(qa[1], kf[1], s[0][0],0,0,0); \
    s[0][1] = MFMA(qa[0], kf[2], z4,0,0,0); s[0][1] = MFMA(qa[1], kf[3], s[0][1],0,0,0); \
    s[1][0] = MFMA(qa[2], kf[0], z4,0,0,0); s[1][0] = MFMA(qa[3], kf[1], s[1][0],0,0,0); \
    s[1][1] = MFMA(qa[2], kf[2], z4,0,0,0); s[1][1] = MFMA(qa[3], kf[3], s[1][1],0,0,0); \
    LOAD_MI(TN); LOAD_K(TN); \
    float p[2][2][4]; \
    _Pragma("unroll") \
    for(int rg=0; rg<2; rg++){ \
      _Pragma("unroll") \
      for(int jg=0; jg<2; jg++){ \
        unsigned long long rv = *(const unsigned long long*)&rdl[RDS2((CUR)*8 + w, jg*16+i16, rg*16+4*g)]; \
        unsigned lo = (unsigned)rv, hi = (unsigned)(rv>>32); \
        float rf0 = bitsf(lo<<16), rf1 = bitsf(lo & 0xffff0000u); \
        float rf2 = bitsf(hi<<16), rf3 = bitsf(hi & 0xffff0000u); \
        p[rg][jg][0] = __expf((s[rg][jg][0] + rf0)*iscale); \
        p[rg][jg][1] = __expf((s[rg][jg][1] + rf1)*iscale); \
        p[rg][jg][2] = __expf((s[rg][jg][2] + rf2)*iscale); \
        p[rg][jg][3] = __expf((s[rg][jg][3] + rf3)*iscale); \
      } \
      _Pragma("unroll") \
      for(int r=0; r<4; r++) l_r[rg*4+r] += p[rg][0][r] + p[rg][1][r]; \
    } \
    _Pragma("unroll") \
    for(int rg=0; rg<2; rg++) \
      _Pragma("unroll") \
      for(int jg=0; jg<2; jg++) \
        _Pragma("unroll") \
        for(int r=0; r<4; r++) \
          p_lds[PS(w, rg*16 + 4*g + r, jg*16 + i16)] = f2bf(p[rg][jg][r]); \
    _Pragma("unroll") \
    for(int rg=0; rg<2; rg++){ \
      short8 pb = *(const short8*)&p_lds[PS(w, rg*16 + i16, 8*g)]; \
      O[0][rg] = MFMA(vf[0], pb, O[0][rg],0,0,0); \
      O[1][rg] = MFMA(vf[1], pb, O[1][rg],0,0,0); \
      O[2][rg] = MFMA(vf[2], pb, O[2][rg],0,0,0); \
      O[3][rg] = MFMA(vf[3], pb, O[3][rg],0,0,0); \
    } \
    LOAD_V(TN); \
  }while(0)

  const int t0 = jh*64;
  // prologue: stage D(t0) into buf0 (one-time wait); preload glB<-t0+1, glA<-t0+2
  LOAD_GL(glA, t0);
  LOAD_MI(t0); LOAD_K(t0); LOAD_V(t0);
  CVT_STORE(glA, 0);
  LOAD_GL(glB, t0+1);
  LOAD_GL(glA, t0+2);

  for(int t2=0; t2<64; t2+=2){
    {
      const int t = t2;
      const int tn = t0 + ((t+1<64)? t+1 : 63);
      const int tp = t0 + ((t+3<64)? t+3 : 63);
      ATTN_ITER(0, glB, tn, tp);
    }
    {
      const int t = t2+1;
      const int tn = t0 + ((t+1<64)? t+1 : 63);
      const int tp = t0 + ((t+3<64)? t+3 : 63);
      ATTN_ITER(1, glA, tn, tp);
    }
  }
  // final: reduce l over the 16 j-lanes, store partials
  #pragma unroll
  for(int dd=1; dd<16; dd<<=1)
    #pragma unroll
    for(int k2=0; k2<8; k2++) l_r[k2] += __shfl_xor(l_r[k2], dd);
  if(i16 == 0){
    #pragma unroll
    for(int rg=0; rg<2; rg++)
      #pragma unroll
      for(int r=0; r<4; r++)
        lpart[((size_t)jh*8 + w)*NN + i0 + rg*16 + 4*g + r] = l_r[rg*4+r];
  }
  #pragma unroll
  for(int rg=0; rg<2; rg++)
    #pragma unroll
    for(int db=0; db<4; db++)
      *(float4_t*)(Opart + ((size_t)jh*NN + i0 + rg*16 + i16)*512 + w*64 + db*16 + 4*g) = O[db][rg];
}

// ---------------- merge the two j-half partials -> ctx bf16 ----------------
__global__ void k_merge(const float* __restrict__ Op, const float* __restrict__ lp,
                        short* __restrict__ ctx){
  int T = blockIdx.x*256 + threadIdx.x;   // 4096*64 threads, 8 cols each
  int i = T >> 6; int c = (T & 63) * 8;
  int h = c >> 6;
  float lA = lp[(size_t)h*NN + i], lB = lp[(size_t)(8+h)*NN + i];
  float inv = 1.0f / (lA + lB);
  const float4_t* a = (const float4_t*)(Op + (size_t)i*512 + c);
  const float4_t* b = (const float4_t*)(Op + ((size_t)NN + i)*512 + c);
  float4_t x0 = a[0], x1 = a[1], y0 = b[0], y1 = b[1];
  short8 o;
  #pragma unroll
  for(int e=0; e<4; e++){
    o[e]   = f2bf((x0[e]+y0[e])*inv);
    o[e+4] = f2bf((x1[e]+y1[e])*inv);
  }
  *(short8*)(ctx + (size_t)i*512 + c) = o;
}

extern "C" void kernel_launch(void* const* d_in, const int* in_sizes, int n_in,
                              void* d_out, int out_size, void* d_ws, size_t ws_size,
                              hipStream_t stream) {
  (void)in_sizes; (void)n_in; (void)out_size; (void)ws_size;
  const float* H    = (const float*)d_in[0];
  const float* Dm   = (const float*)d_in[1];
  const float* mask = (const float*)d_in[2];
  const float* W    = (const float*)d_in[3];
  const float* Wout = (const float*)d_in[4];
  float* out = (float*)d_out;

  char* ws = (char*)d_ws;
  size_t off = 0;
  auto carve = [&](size_t bytes)->char*{
    char* p = ws + off; off += (bytes + 255) & ~(size_t)255; return p;
  };
  short* Hb    = (short*)carve((size_t)4096*512*2);
  short* Wt    = (short*)carve((size_t)1664*512*2);
  short* Wot   = (short*)carve((size_t)512*512*2);
  float* H2    = (float*)carve((size_t)4096*1664*4);
  short* Qp    = (short*)carve((size_t)8*256*2*64*8*2);
  short* Kp    = (short*)carve((size_t)8*256*2*64*8*2);
  short* Vp    = (short*)carve((size_t)8*128*4*64*8*2);
  short* Rp    = (short*)carve((size_t)4096*256*2);
  short* ctxb  = (short*)carve((size_t)4096*512*2);
  float* Opart = (float*)carve((size_t)2*4096*512*4);
  float* lp    = (float*)carve((size_t)2*8*4096*4);

  // 1) convert H to bf16; transpose+convert W, Wout
  k_cvt<<<2048, 256, 0, stream>>>(H, Hb, 4096*512/4);
  k_trans<<<dim3(52,16), dim3(32,8), 0, stream>>>(W, Wt, 512, 1664);
  k_trans<<<dim3(16,16), dim3(32,8), 0, stream>>>(Wout, Wot, 512, 512);
  // 2) projection GEMM: H2 = Hb @ Wt^T  (4096 x 1664, K=512)
  k_gemm<<<dim3(64,26), 256, 0, stream>>>(Hb, Wt, H2, 4096, 1664, 512);
  // 3) pack Q/K/V/R fragment layouts
  k_pack<<<3584, 256, 0, stream>>>(H2, Qp, Kp, Vp, Rp);
  // 4) fused attention with relative bias D (LDS-staged D, 2-deep dense bursts)
  k_attn<<<256, 512, 0, stream>>>(Dm, mask, Qp, Kp, Vp, Rp, Opart, lp);
  // 5) merge partials -> ctx bf16
  k_merge<<<1024, 256, 0, stream>>>(Opart, lp, ctxb);
  // 6) output GEMM: out = ctx @ Wout  (4096 x 512, K=512)
  k_gemm<<<dim3(64,8), 256, 0, stream>>>(ctxb, Wot, out, 4096, 512, 512);
}

// Round 13
// 287.889 us; speedup vs baseline: 1.4813x; 1.4813x over previous
//
#include <hip/hip_runtime.h>
#include <hip/hip_bf16.h>

#define NN 4096
#define NH 8
#define TOT 208
#define NPROJ 1664

typedef __attribute__((ext_vector_type(8))) short short8;
typedef __attribute__((ext_vector_type(4))) short short4_t;
typedef __attribute__((ext_vector_type(4))) float float4_t;

#define MFMA __builtin_amdgcn_mfma_f32_16x16x32_bf16

__device__ __forceinline__ short f2bf(float f){
  union { float f; unsigned u; } v; v.f = f;
  unsigned r = v.u + 0x7fffu + ((v.u >> 16) & 1u);
  return (short)(r >> 16);
}

__device__ __forceinline__ float bitsf(unsigned u){
  union { unsigned u; float f; } v; v.u = u; return v.f;
}

// barrier without vmcnt drain: LDS visibility needs lgkmcnt(0) only.
#define BAR() do{ \
    asm volatile("s_waitcnt lgkmcnt(0)" ::: "memory"); \
    __builtin_amdgcn_s_barrier(); \
    asm volatile("" ::: "memory"); \
  }while(0)

// ---------------- elementwise f32 -> bf16 (x4 per thread) ----------------
__global__ void k_cvt(const float* __restrict__ in, short* __restrict__ out, int n4){
  int i = blockIdx.x*256 + threadIdx.x;
  if(i >= n4) return;
  float4_t v = *(const float4_t*)(in + (size_t)i*4);
  short4_t o;
  o[0]=f2bf(v[0]); o[1]=f2bf(v[1]); o[2]=f2bf(v[2]); o[3]=f2bf(v[3]);
  *(short4_t*)(out + (size_t)i*4) = o;
}

// ---------------- transpose + cvt: out[c][r] = bf16(in[r][c]) ----------------
__global__ void k_trans(const float* __restrict__ in, short* __restrict__ out, int R, int C){
  __shared__ float tile[32][33];
  int bc = blockIdx.x*32, br = blockIdx.y*32;
  int tx = threadIdx.x, ty = threadIdx.y;
  #pragma unroll
  for(int dy=0; dy<32; dy+=8){
    int r = br+ty+dy, c = bc+tx;
    if(r<R && c<C) tile[ty+dy][tx] = in[(size_t)r*C + c];
  }
  __syncthreads();
  #pragma unroll
  for(int dy=0; dy<32; dy+=8){
    int c = bc+ty+dy, r = br+tx;
    if(c<C && r<R) out[(size_t)c*R + r] = f2bf(tile[tx][ty+dy]);
  }
}

// ---------------- generic bf16 GEMM: C[M][Ncols] f32 = A[M][K] * Bt[Ncols][K]^T ----------------
__global__ __launch_bounds__(256) void k_gemm(
    const short* __restrict__ A, const short* __restrict__ Bt, float* __restrict__ C,
    int M, int Ncols, int K)
{
  __shared__ __align__(16) short As[2][2048];
  __shared__ __align__(16) short Bs[2][2048];
  const int tid = threadIdx.x;
  const int l = tid & 63, w = tid >> 6;
  const int wm = w >> 1, wn = w & 1;
  const int g = l >> 4, i16 = l & 15;
  const size_t bm = (size_t)blockIdx.x * 64, bn = (size_t)blockIdx.y * 64;
  const int r = tid >> 2, cb = tid & 3;
  const int dst = r*32 + ((cb ^ (r&3))*8);
  const short* Ag = A + (bm + (size_t)r)*K + cb*8;
  const short* Bg = Bt + (bn + (size_t)r)*K + cb*8;
  float4_t z4 = {0.f,0.f,0.f,0.f};
  float4_t acc00=z4, acc01=z4, acc10=z4, acc11=z4;
  short8 ta = *(const short8*)(Ag);
  short8 tb = *(const short8*)(Bg);
  *(short8*)&As[0][dst] = ta;
  *(short8*)&Bs[0][dst] = tb;
  const int nk = K >> 5;
  int c = 0;
  const int swa = (g ^ (i16&3))*8;
  for(int kt=0; kt<nk; kt++){
    __syncthreads();
    if(kt+1 < nk){
      ta = *(const short8*)(Ag + (kt+1)*32);
      tb = *(const short8*)(Bg + (kt+1)*32);
    }
    short8 a0 = *(const short8*)&As[c][(wm*32 + i16)*32 + swa];
    short8 a1 = *(const short8*)&As[c][(wm*32 + 16 + i16)*32 + swa];
    short8 b0 = *(const short8*)&Bs[c][(wn*32 + i16)*32 + swa];
    short8 b1 = *(const short8*)&Bs[c][(wn*32 + 16 + i16)*32 + swa];
    acc00 = MFMA(a0,b0,acc00,0,0,0); acc01 = MFMA(a0,b1,acc01,0,0,0);
    acc10 = MFMA(a1,b0,acc10,0,0,0); acc11 = MFMA(a1,b1,acc11,0,0,0);
    if(kt+1 < nk){
      *(short8*)&As[c^1][dst] = ta;
      *(short8*)&Bs[c^1][dst] = tb;
    }
    c ^= 1;
  }
  #pragma unroll
  for(int rr=0; rr<4; rr++){
    C[(bm + wm*32 +      4*g + rr)*(size_t)Ncols + bn + wn*32 + i16]      = acc00[rr];
    C[(bm + wm*32 +      4*g + rr)*(size_t)Ncols + bn + wn*32 + 16 + i16] = acc01[rr];
    C[(bm + wm*32 + 16 + 4*g + rr)*(size_t)Ncols + bn + wn*32 + i16]      = acc10[rr];
    C[(bm + wm*32 + 16 + 4*g + rr)*(size_t)Ncols + bn + wn*32 + 16 + i16] = acc11[rr];
  }
}

// ---------------- pack H2 -> Qp/Kp/Vp/Rp fragment layouts ----------------
__global__ void k_pack(const float* __restrict__ H2, short* __restrict__ Qp,
                       short* __restrict__ Kp, short* __restrict__ Vp, short* __restrict__ Rp){
  int T = blockIdx.x*256 + threadIdx.x;
  if(T < 262144){
    int l = T & 63; int rest = T >> 6;
    int kb = rest & 1; rest >>= 1;
    int it = rest & 255; int h = rest >> 8;
    int i = it*16 + (l & 15);
    int col = h*TOT + kb*32 + 8*(l>>4);
    const float* s = H2 + (size_t)i*NPROJ + col;
    short8 v;
    #pragma unroll
    for(int e=0;e<8;e++) v[e] = f2bf(s[e]);
    *(short8*)(Qp + (size_t)T*8) = v;
  } else if(T < 524288){
    int T2 = T - 262144;
    int l = T2 & 63; int rest = T2 >> 6;
    int kb = rest & 1; rest >>= 1;
    int it = rest & 255; int h = rest >> 8;
    int i = it*16 + (l & 15);
    int col = h*TOT + 64 + kb*32 + 8*(l>>4);
    const float* s = H2 + (size_t)i*NPROJ + col;
    short8 v;
    #pragma unroll
    for(int e=0;e<8;e++) v[e] = f2bf(s[e]);
    *(short8*)(Kp + (size_t)T2*8) = v;
  } else if(T < 786432){
    int T2 = T - 524288;
    int l = T2 & 63; int rest = T2 >> 6;
    int db = rest & 3; rest >>= 2;
    int jt = rest & 127; int h = rest >> 7;
    int col = h*TOT + 128 + db*16 + (l & 15);
    int j0 = jt*32 + 8*(l>>4);
    short8 v;
    #pragma unroll
    for(int e=0;e<8;e++) v[e] = f2bf(H2[(size_t)(j0+e)*NPROJ + col]);
    *(short8*)(Vp + (size_t)T2*8) = v;
  } else {
    int T2 = T - 786432;
    int half = T2 & 1; int hh = (T2>>1) & 15; int i = T2 >> 5;
    short8 v;
    #pragma unroll
    for(int e=0;e<8;e++) v[e] = 0;
    if(hh < 8){
      const float* s = H2 + (size_t)i*NPROJ + hh*TOT + 192 + half*8;
      #pragma unroll
      for(int e=0;e<8;e++) v[e] = f2bf(s[e]);
    }
    *(short8*)(Rp + (size_t)T2*8) = v;
  }
}

// ---------------- fused attention, QBLK=32, j-halves, LDS-staged D ----------------
// grid 256: block = (i-tile of 32 rows = bid>>1, j-half = bid&1), 8 waves = 8 heads.
// D staging: each wave loads its 4 D rows as 8 DENSE 1KB bursts (64 lanes x 16B,
// all lanes active) into 32 f32 regs; converts to bf16 + ds_write into a
// double-buffered LDS tile one iteration later (wave-private rows -> same-wave
// visibility). Producer reads MFMA B-frags from LDS.
// ORDERING: LOAD_K/LOAD_MI(tn) must come AFTER the consumer's QK MFMAs (R10 bug).
// NOTE (R9/R12): register prefetch deeper than 1 tile spills -> never do it.
#define RDS2(h,j,i) (((h)*32+(j))*36+(i))
#define PS(ww,row,j) (((ww)*32+(row))*40+(j))

__global__ __launch_bounds__(512) void k_attn(
    const float* __restrict__ Dm, const float* __restrict__ mask,
    const short* __restrict__ Qp, const short* __restrict__ Kp,
    const short* __restrict__ Vp, const short* __restrict__ Rp,
    float* __restrict__ Opart, float* __restrict__ lpart)
{
  __shared__ __align__(16) short Dlds[2*32*512];   // [2 buf][32 row][32 j][16 r] bf16 = 64KB
  __shared__ __align__(16) short rdl[18432];        // [2 buf][8 h][32 j][36 i] bf16 = 36KB
  __shared__ __align__(16) short p_lds[10240];      // [8 w][32 row][40 j] bf16 = 20KB

  const int tid = threadIdx.x;
  const int l = tid & 63, w = tid >> 6;
  const int g = l >> 4, i16 = l & 15;
  const int IT = blockIdx.x >> 1, jh = blockIdx.x & 1;
  const int i0 = IT * 32;
  const float iscale = 0.11180339887498949f;   // 1/sqrt(80)
  const float msc    = 8.944271909999159f;     // sqrt(80)

  // persistent Q A-frags: rows rg*16 (rg=0,1), kb=0,1
  short8 qa[4];
  #pragma unroll
  for(int rg=0; rg<2; rg++)
    #pragma unroll
    for(int kb=0; kb<2; kb++)
      qa[rg*2+kb] = *(const short8*)(Qp + (((size_t)w*256 + IT*2+rg)*2 + kb)*512 + (size_t)l*8);

  // persistent R A-frags for producer rows 4w..4w+3 (K zero-padded 16->32)
  short8 ra[4];
  #pragma unroll
  for(int row=0; row<4; row++)
    #pragma unroll
    for(int e=0; e<8; e++) ra[row][e] = 0;
  if(g < 2){
    #pragma unroll
    for(int row=0; row<4; row++)
      ra[row] = *(const short8*)(Rp + (size_t)(i0+4*w+row)*256 + i16*16 + 8*g);
  }

  float4_t z4 = {0.f,0.f,0.f,0.f};
  float4_t O[4][2];   // [db][rg]
  #pragma unroll
  for(int db=0; db<4; db++){ O[db][0]=z4; O[db][1]=z4; }
  float l_r[8];
  #pragma unroll
  for(int k2=0;k2<8;k2++) l_r[k2]=0.f;

  // D staging registers: 8 x float4 (dense 1KB bursts) — ALL 64 lanes active
  float4_t gl[4][2];
  float mi[4][2];
  short8 kf[4], vf[4];

  // dense staging loads: instr (row,half) covers 1KB contiguous
#define LOAD_GL(ts) do{ \
    _Pragma("unroll") \
    for(int row=0; row<4; row++){ \
      const float* rb = Dm + ((size_t)(i0+4*w+row)*NN + (size_t)(ts)*32)*16; \
      gl[row][0] = *(const float4_t*)(rb + l*4); \
      gl[row][1] = *(const float4_t*)(rb + 256 + l*4); \
    } }while(0)

  // convert gl (f32) -> bf16 and store into Dlds[bufb] (wave-private rows).
  // Ends with a compiler memory fence: the ULL stores type-pun the short array;
  // don't let later short8 reads of Dlds be hoisted above them.
#define CVT_STORE(bufb) do{ \
    short* dbp = Dlds + (bufb)*16384; \
    const int jw = (l>>2), r0 = 4*(l&3); \
    _Pragma("unroll") \
    for(int row=0; row<4; row++){ \
      _Pragma("unroll") \
      for(int half=0; half<2; half++){ \
        unsigned u0,u1; float4_t v = gl[row][half]; \
        asm("v_cvt_pk_bf16_f32 %0, %1, %2" : "=v"(u0) : "v"(v[0]), "v"(v[1])); \
        asm("v_cvt_pk_bf16_f32 %0, %1, %2" : "=v"(u1) : "v"(v[2]), "v"(v[3])); \
        unsigned long long pk = (unsigned long long)u0 | ((unsigned long long)u1<<32); \
        *(unsigned long long*)(dbp + (4*w+row)*512 + (half*16+jw)*16 + r0) = pk; \
      } } \
    asm volatile("" ::: "memory"); \
  }while(0)

#define LOAD_MI(tt) do{ \
    size_t jj = (size_t)(tt)*32 + i16; \
    mi[0][0] = mask[(size_t)(i0+4*w+0)*NN + jj] * msc; \
    mi[0][1] = mask[(size_t)(i0+4*w+0)*NN + jj + 16] * msc; \
    mi[1][0] = mask[(size_t)(i0+4*w+1)*NN + jj] * msc; \
    mi[1][1] = mask[(size_t)(i0+4*w+1)*NN + jj + 16] * msc; \
    mi[2][0] = mask[(size_t)(i0+4*w+2)*NN + jj] * msc; \
    mi[2][1] = mask[(size_t)(i0+4*w+2)*NN + jj + 16] * msc; \
    mi[3][0] = mask[(size_t)(i0+4*w+3)*NN + jj] * msc; \
    mi[3][1] = mask[(size_t)(i0+4*w+3)*NN + jj + 16] * msc; }while(0)

#define LOAD_K(tt) do{ \
    const short* kp = Kp + (((size_t)w*256 + (size_t)(tt)*2)*2)*512 + (size_t)l*8; \
    kf[0] = *(const short8*)(kp);        kf[1] = *(const short8*)(kp+512); \
    kf[2] = *(const short8*)(kp+1024);   kf[3] = *(const short8*)(kp+1536); }while(0)

#define LOAD_V(tt) do{ \
    const short* vp = Vp + (((size_t)w*128 + (size_t)(tt))*4)*512 + (size_t)l*8; \
    vf[0] = *(const short8*)(vp);        vf[1] = *(const short8*)(vp+512); \
    vf[2] = *(const short8*)(vp+1024);   vf[3] = *(const short8*)(vp+1536); }while(0)

  const int t0 = jh*64;
  // prologue: stage D(t0) into buf0 (one-time immediate wait), start D(t0+1)
  LOAD_GL(t0);
  LOAD_MI(t0); LOAD_K(t0); LOAD_V(t0);
  CVT_STORE(0);
  LOAD_GL(t0+1);

  for(int t=0; t<64; t++){
    const int cur = t & 1;
    const int tn = (t<63) ? t0+t+1 : t0+63;
    const int tp = (t<62) ? t0+t+2 : t0+63;
    // ---- producer: B-frags from Dlds[cur], RD for rows 4w..4w+3, heads = MFMA M ----
    const short* dcur = Dlds + cur*16384;
    short8 zf;
    #pragma unroll
    for(int e=0;e<8;e++) zf[e] = 0;
    #pragma unroll
    for(int row=0; row<4; row++){
      short8 db0 = zf, db1 = zf;
      if(g < 2){
        db0 = *(const short8*)(dcur + (4*w+row)*512 + i16*16      + 8*g);
        db1 = *(const short8*)(dcur + (4*w+row)*512 + (16+i16)*16 + 8*g);
      }
      float4_t c0 = {mi[row][0],mi[row][0],mi[row][0],mi[row][0]};
      float4_t c1 = {mi[row][1],mi[row][1],mi[row][1],mi[row][1]};
      c0 = MFMA(ra[row], db0, c0,0,0,0);
      c1 = MFMA(ra[row], db1, c1,0,0,0);
      if(g < 2){
        int ib = 4*w + row;
        #pragma unroll
        for(int r=0; r<4; r++){
          rdl[RDS2(cur*8 + 4*g+r, i16,    ib)] = f2bf(c0[r]);
          rdl[RDS2(cur*8 + 4*g+r, 16+i16, ib)] = f2bf(c1[r]);
        }
      }
    }
    // ---- stage D(t+1) into other buffer; issue D(t+2) dense bursts ----
    CVT_STORE(cur^1);
    LOAD_GL(tp);
    BAR();
    // ---- consumer: head w, 32 rows x 32 j (kf/mi of tile t consumed HERE) ----
    float4_t s[2][2];
    s[0][0] = MFMA(qa[0], kf[0], z4,0,0,0); s[0][0] = MFMA(qa[1], kf[1], s[0][0],0,0,0);
    s[0][1] = MFMA(qa[0], kf[2], z4,0,0,0); s[0][1] = MFMA(qa[1], kf[3], s[0][1],0,0,0);
    s[1][0] = MFMA(qa[2], kf[0], z4,0,0,0); s[1][0] = MFMA(qa[3], kf[1], s[1][0],0,0,0);
    s[1][1] = MFMA(qa[2], kf[2], z4,0,0,0); s[1][1] = MFMA(qa[3], kf[3], s[1][1],0,0,0);
    // NOW safe to prefetch next tile's mask/K (kf consumed by the MFMAs above)
    LOAD_MI(tn); LOAD_K(tn);
    float p[2][2][4];
    #pragma unroll
    for(int rg=0; rg<2; rg++){
      #pragma unroll
      for(int jg=0; jg<2; jg++){
        unsigned long long rv = *(const unsigned long long*)&rdl[RDS2(cur*8 + w, jg*16+i16, rg*16+4*g)];
        unsigned lo = (unsigned)rv, hi = (unsigned)(rv>>32);
        float rf0 = bitsf(lo<<16), rf1 = bitsf(lo & 0xffff0000u);
        float rf2 = bitsf(hi<<16), rf3 = bitsf(hi & 0xffff0000u);
        p[rg][jg][0] = __expf((s[rg][jg][0] + rf0)*iscale);
        p[rg][jg][1] = __expf((s[rg][jg][1] + rf1)*iscale);
        p[rg][jg][2] = __expf((s[rg][jg][2] + rf2)*iscale);
        p[rg][jg][3] = __expf((s[rg][jg][3] + rf3)*iscale);
      }
      #pragma unroll
      for(int r=0; r<4; r++) l_r[rg*4+r] += p[rg][0][r] + p[rg][1][r];
    }
    #pragma unroll
    for(int rg=0; rg<2; rg++)
      #pragma unroll
      for(int jg=0; jg<2; jg++)
        #pragma unroll
        for(int r=0; r<4; r++)
          p_lds[PS(w, rg*16 + 4*g + r, jg*16 + i16)] = f2bf(p[rg][jg][r]);
    #pragma unroll
    for(int rg=0; rg<2; rg++){
      short8 pb = *(const short8*)&p_lds[PS(w, rg*16 + i16, 8*g)];
      O[0][rg] = MFMA(vf[0], pb, O[0][rg],0,0,0);
      O[1][rg] = MFMA(vf[1], pb, O[1][rg],0,0,0);
      O[2][rg] = MFMA(vf[2], pb, O[2][rg],0,0,0);
      O[3][rg] = MFMA(vf[3], pb, O[3][rg],0,0,0);
    }
    LOAD_V(tn);
  }
  // final: reduce l over the 16 j-lanes, store partials
  #pragma unroll
  for(int dd=1; dd<16; dd<<=1)
    #pragma unroll
    for(int k2=0; k2<8; k2++) l_r[k2] += __shfl_xor(l_r[k2], dd);
  if(i16 == 0){
    #pragma unroll
    for(int rg=0; rg<2; rg++)
      #pragma unroll
      for(int r=0; r<4; r++)
        lpart[((size_t)jh*8 + w)*NN + i0 + rg*16 + 4*g + r] = l_r[rg*4+r];
  }
  #pragma unroll
  for(int rg=0; rg<2; rg++)
    #pragma unroll
    for(int db=0; db<4; db++)
      *(float4_t*)(Opart + ((size_t)jh*NN + i0 + rg*16 + i16)*512 + w*64 + db*16 + 4*g) = O[db][rg];
}

// ---------------- merge the two j-half partials -> ctx bf16 ----------------
__global__ void k_merge(const float* __restrict__ Op, const float* __restrict__ lp,
                        short* __restrict__ ctx){
  int T = blockIdx.x*256 + threadIdx.x;   // 4096*64 threads, 8 cols each
  int i = T >> 6; int c = (T & 63) * 8;
  int h = c >> 6;
  float lA = lp[(size_t)h*NN + i], lB = lp[(size_t)(8+h)*NN + i];
  float inv = 1.0f / (lA + lB);
  const float4_t* a = (const float4_t*)(Op + (size_t)i*512 + c);
  const float4_t* b = (const float4_t*)(Op + ((size_t)NN + i)*512 + c);
  float4_t x0 = a[0], x1 = a[1], y0 = b[0], y1 = b[1];
  short8 o;
  #pragma unroll
  for(int e=0; e<4; e++){
    o[e]   = f2bf((x0[e]+y0[e])*inv);
    o[e+4] = f2bf((x1[e]+y1[e])*inv);
  }
  *(short8*)(ctx + (size_t)i*512 + c) = o;
}

extern "C" void kernel_launch(void* const* d_in, const int* in_sizes, int n_in,
                              void* d_out, int out_size, void* d_ws, size_t ws_size,
                              hipStream_t stream) {
  (void)in_sizes; (void)n_in; (void)out_size; (void)ws_size;
  const float* H    = (const float*)d_in[0];
  const float* Dm   = (const float*)d_in[1];
  const float* mask = (const float*)d_in[2];
  const float* W    = (const float*)d_in[3];
  const float* Wout = (const float*)d_in[4];
  float* out = (float*)d_out;

  char* ws = (char*)d_ws;
  size_t off = 0;
  auto carve = [&](size_t bytes)->char*{
    char* p = ws + off; off += (bytes + 255) & ~(size_t)255; return p;
  };
  short* Hb    = (short*)carve((size_t)4096*512*2);
  short* Wt    = (short*)carve((size_t)1664*512*2);
  short* Wot   = (short*)carve((size_t)512*512*2);
  float* H2    = (float*)carve((size_t)4096*1664*4);
  short* Qp    = (short*)carve((size_t)8*256*2*64*8*2);
  short* Kp    = (short*)carve((size_t)8*256*2*64*8*2);
  short* Vp    = (short*)carve((size_t)8*128*4*64*8*2);
  short* Rp    = (short*)carve((size_t)4096*256*2);
  short* ctxb  = (short*)carve((size_t)4096*512*2);
  float* Opart = (float*)carve((size_t)2*4096*512*4);
  float* lp    = (float*)carve((size_t)2*8*4096*4);

  // 1) convert H to bf16; transpose+convert W, Wout
  k_cvt<<<2048, 256, 0, stream>>>(H, Hb, 4096*512/4);
  k_trans<<<dim3(52,16), dim3(32,8), 0, stream>>>(W, Wt, 512, 1664);
  k_trans<<<dim3(16,16), dim3(32,8), 0, stream>>>(Wout, Wot, 512, 512);
  // 2) projection GEMM: H2 = Hb @ Wt^T  (4096 x 1664, K=512)
  k_gemm<<<dim3(64,26), 256, 0, stream>>>(Hb, Wt, H2, 4096, 1664, 512);
  // 3) pack Q/K/V/R fragment layouts
  k_pack<<<3584, 256, 0, stream>>>(H2, Qp, Kp, Vp, Rp);
  // 4) fused attention with relative bias D (LDS-staged D, dense bursts)
  k_attn<<<256, 512, 0, stream>>>(Dm, mask, Qp, Kp, Vp, Rp, Opart, lp);
  // 5) merge partials -> ctx bf16
  k_merge<<<1024, 256, 0, stream>>>(Opart, lp, ctxb);
  // 6) output GEMM: out = ctx @ Wout  (4096 x 512, K=512)
  k_gemm<<<dim3(64,8), 256, 0, stream>>>(ctxb, Wot, out, 4096, 512, 512);
}

// Round 14
// 286.286 us; speedup vs baseline: 1.4896x; 1.0056x over previous
//
#include <hip/hip_runtime.h>
#include <hip/hip_bf16.h>

#define NN 4096
#define NH 8
#define TOT 208
#define NPROJ 1664

typedef __attribute__((ext_vector_type(8))) short short8;
typedef __attribute__((ext_vector_type(4))) short short4_t;
typedef __attribute__((ext_vector_type(4))) float float4_t;

#define MFMA __builtin_amdgcn_mfma_f32_16x16x32_bf16

__device__ __forceinline__ short f2bf(float f){
  union { float f; unsigned u; } v; v.f = f;
  unsigned r = v.u + 0x7fffu + ((v.u >> 16) & 1u);
  return (short)(r >> 16);
}

__device__ __forceinline__ float bitsf(unsigned u){
  union { unsigned u; float f; } v; v.u = u; return v.f;
}

// barrier without vmcnt drain: LDS visibility needs lgkmcnt(0) only.
#define BAR() do{ \
    asm volatile("s_waitcnt lgkmcnt(0)" ::: "memory"); \
    __builtin_amdgcn_s_barrier(); \
    asm volatile("" ::: "memory"); \
  }while(0)

// ---------------- elementwise f32 -> bf16 (x4 per thread) ----------------
__global__ void k_cvt(const float* __restrict__ in, short* __restrict__ out, int n4){
  int i = blockIdx.x*256 + threadIdx.x;
  if(i >= n4) return;
  float4_t v = *(const float4_t*)(in + (size_t)i*4);
  short4_t o;
  o[0]=f2bf(v[0]); o[1]=f2bf(v[1]); o[2]=f2bf(v[2]); o[3]=f2bf(v[3]);
  *(short4_t*)(out + (size_t)i*4) = o;
}

// ---------------- transpose + cvt: out[c][r] = bf16(in[r][c]) ----------------
__global__ void k_trans(const float* __restrict__ in, short* __restrict__ out, int R, int C){
  __shared__ float tile[32][33];
  int bc = blockIdx.x*32, br = blockIdx.y*32;
  int tx = threadIdx.x, ty = threadIdx.y;
  #pragma unroll
  for(int dy=0; dy<32; dy+=8){
    int r = br+ty+dy, c = bc+tx;
    if(r<R && c<C) tile[ty+dy][tx] = in[(size_t)r*C + c];
  }
  __syncthreads();
  #pragma unroll
  for(int dy=0; dy<32; dy+=8){
    int c = bc+ty+dy, r = br+tx;
    if(c<C && r<R) out[(size_t)c*R + r] = f2bf(tile[tx][ty+dy]);
  }
}

// -------- generic bf16 GEMM: C[M][Ncols] = A[M][K] * Bt[Ncols][K]^T --------
// OUTBF=0: C is f32. OUTBF=1: C is bf16 (f2bf of the f32 accumulator — same
// single rounding as the old f32-write + separate-convert path; bit-identical).
template<int OUTBF>
__global__ __launch_bounds__(256) void k_gemm_t(
    const short* __restrict__ A, const short* __restrict__ Bt, void* __restrict__ Cv,
    int M, int Ncols, int K)
{
  __shared__ __align__(16) short As[2][2048];
  __shared__ __align__(16) short Bs[2][2048];
  const int tid = threadIdx.x;
  const int l = tid & 63, w = tid >> 6;
  const int wm = w >> 1, wn = w & 1;
  const int g = l >> 4, i16 = l & 15;
  const size_t bm = (size_t)blockIdx.x * 64, bn = (size_t)blockIdx.y * 64;
  const int r = tid >> 2, cb = tid & 3;
  const int dst = r*32 + ((cb ^ (r&3))*8);
  const short* Ag = A + (bm + (size_t)r)*K + cb*8;
  const short* Bg = Bt + (bn + (size_t)r)*K + cb*8;
  float4_t z4 = {0.f,0.f,0.f,0.f};
  float4_t acc00=z4, acc01=z4, acc10=z4, acc11=z4;
  short8 ta = *(const short8*)(Ag);
  short8 tb = *(const short8*)(Bg);
  *(short8*)&As[0][dst] = ta;
  *(short8*)&Bs[0][dst] = tb;
  const int nk = K >> 5;
  int c = 0;
  const int swa = (g ^ (i16&3))*8;
  for(int kt=0; kt<nk; kt++){
    __syncthreads();
    if(kt+1 < nk){
      ta = *(const short8*)(Ag + (kt+1)*32);
      tb = *(const short8*)(Bg + (kt+1)*32);
    }
    short8 a0 = *(const short8*)&As[c][(wm*32 + i16)*32 + swa];
    short8 a1 = *(const short8*)&As[c][(wm*32 + 16 + i16)*32 + swa];
    short8 b0 = *(const short8*)&Bs[c][(wn*32 + i16)*32 + swa];
    short8 b1 = *(const short8*)&Bs[c][(wn*32 + 16 + i16)*32 + swa];
    acc00 = MFMA(a0,b0,acc00,0,0,0); acc01 = MFMA(a0,b1,acc01,0,0,0);
    acc10 = MFMA(a1,b0,acc10,0,0,0); acc11 = MFMA(a1,b1,acc11,0,0,0);
    if(kt+1 < nk){
      *(short8*)&As[c^1][dst] = ta;
      *(short8*)&Bs[c^1][dst] = tb;
    }
    c ^= 1;
  }
  #pragma unroll
  for(int rr=0; rr<4; rr++){
    size_t r0 = (bm + wm*32 +      4*g + rr)*(size_t)Ncols + bn + wn*32;
    size_t r1 = (bm + wm*32 + 16 + 4*g + rr)*(size_t)Ncols + bn + wn*32;
    if(OUTBF){
      short* C = (short*)Cv;
      C[r0 + i16]      = f2bf(acc00[rr]);
      C[r0 + 16 + i16] = f2bf(acc01[rr]);
      C[r1 + i16]      = f2bf(acc10[rr]);
      C[r1 + 16 + i16] = f2bf(acc11[rr]);
    } else {
      float* C = (float*)Cv;
      C[r0 + i16]      = acc00[rr];
      C[r0 + 16 + i16] = acc01[rr];
      C[r1 + i16]      = acc10[rr];
      C[r1 + 16 + i16] = acc11[rr];
    }
  }
}

// ---------------- pack H2 (bf16) -> Qp/Kp/Vp/Rp fragment layouts ----------------
__global__ void k_pack(const short* __restrict__ H2, short* __restrict__ Qp,
                       short* __restrict__ Kp, short* __restrict__ Vp, short* __restrict__ Rp){
  int T = blockIdx.x*256 + threadIdx.x;
  if(T < 262144){
    int l = T & 63; int rest = T >> 6;
    int kb = rest & 1; rest >>= 1;
    int it = rest & 255; int h = rest >> 8;
    int i = it*16 + (l & 15);
    int col = h*TOT + kb*32 + 8*(l>>4);
    const short* s = H2 + (size_t)i*NPROJ + col;
    short8 v;
    #pragma unroll
    for(int e=0;e<8;e++) v[e] = s[e];
    *(short8*)(Qp + (size_t)T*8) = v;
  } else if(T < 524288){
    int T2 = T - 262144;
    int l = T2 & 63; int rest = T2 >> 6;
    int kb = rest & 1; rest >>= 1;
    int it = rest & 255; int h = rest >> 8;
    int i = it*16 + (l & 15);
    int col = h*TOT + 64 + kb*32 + 8*(l>>4);
    const short* s = H2 + (size_t)i*NPROJ + col;
    short8 v;
    #pragma unroll
    for(int e=0;e<8;e++) v[e] = s[e];
    *(short8*)(Kp + (size_t)T2*8) = v;
  } else if(T < 786432){
    int T2 = T - 524288;
    int l = T2 & 63; int rest = T2 >> 6;
    int db = rest & 3; rest >>= 2;
    int jt = rest & 127; int h = rest >> 7;
    int col = h*TOT + 128 + db*16 + (l & 15);
    int j0 = jt*32 + 8*(l>>4);
    short8 v;
    #pragma unroll
    for(int e=0;e<8;e++) v[e] = H2[(size_t)(j0+e)*NPROJ + col];
    *(short8*)(Vp + (size_t)T2*8) = v;
  } else {
    int T2 = T - 786432;
    int half = T2 & 1; int hh = (T2>>1) & 15; int i = T2 >> 5;
    short8 v;
    #pragma unroll
    for(int e=0;e<8;e++) v[e] = 0;
    if(hh < 8){
      const short* s = H2 + (size_t)i*NPROJ + hh*TOT + 192 + half*8;
      #pragma unroll
      for(int e=0;e<8;e++) v[e] = s[e];
    }
    *(short8*)(Rp + (size_t)T2*8) = v;
  }
}

// ---------------- fused attention, QBLK=32, j-halves, LDS-staged D ----------------
// grid 256: block = (i-tile of 32 rows = bid>>1, j-half = bid&1), 8 waves = 8 heads.
// D staging: each wave loads its 4 D rows as 8 DENSE 1KB bursts (64 lanes x 16B,
// all lanes active) into 32 f32 regs; converts to bf16 + ds_write into a
// double-buffered LDS tile one iteration later (wave-private rows -> same-wave
// visibility). Producer reads MFMA B-frags from LDS.
// ORDERING: LOAD_K/LOAD_MI(tn) must come AFTER the consumer's QK MFMAs (R10 bug).
// NOTE (R9/R12): register prefetch deeper than 1 tile spills -> never do it.
#define RDS2(h,j,i) (((h)*32+(j))*36+(i))
#define PS(ww,row,j) (((ww)*32+(row))*40+(j))

__global__ __launch_bounds__(512) void k_attn(
    const float* __restrict__ Dm, const float* __restrict__ mask,
    const short* __restrict__ Qp, const short* __restrict__ Kp,
    const short* __restrict__ Vp, const short* __restrict__ Rp,
    float* __restrict__ Opart, float* __restrict__ lpart)
{
  __shared__ __align__(16) short Dlds[2*32*512];   // [2 buf][32 row][32 j][16 r] bf16 = 64KB
  __shared__ __align__(16) short rdl[18432];        // [2 buf][8 h][32 j][36 i] bf16 = 36KB
  __shared__ __align__(16) short p_lds[10240];      // [8 w][32 row][40 j] bf16 = 20KB

  const int tid = threadIdx.x;
  const int l = tid & 63, w = tid >> 6;
  const int g = l >> 4, i16 = l & 15;
  const int IT = blockIdx.x >> 1, jh = blockIdx.x & 1;
  const int i0 = IT * 32;
  const float iscale = 0.11180339887498949f;   // 1/sqrt(80)
  const float msc    = 8.944271909999159f;     // sqrt(80)

  // persistent Q A-frags: rows rg*16 (rg=0,1), kb=0,1
  short8 qa[4];
  #pragma unroll
  for(int rg=0; rg<2; rg++)
    #pragma unroll
    for(int kb=0; kb<2; kb++)
      qa[rg*2+kb] = *(const short8*)(Qp + (((size_t)w*256 + IT*2+rg)*2 + kb)*512 + (size_t)l*8);

  // persistent R A-frags for producer rows 4w..4w+3 (K zero-padded 16->32)
  short8 ra[4];
  #pragma unroll
  for(int row=0; row<4; row++)
    #pragma unroll
    for(int e=0; e<8; e++) ra[row][e] = 0;
  if(g < 2){
    #pragma unroll
    for(int row=0; row<4; row++)
      ra[row] = *(const short8*)(Rp + (size_t)(i0+4*w+row)*256 + i16*16 + 8*g);
  }

  float4_t z4 = {0.f,0.f,0.f,0.f};
  float4_t O[4][2];   // [db][rg]
  #pragma unroll
  for(int db=0; db<4; db++){ O[db][0]=z4; O[db][1]=z4; }
  float l_r[8];
  #pragma unroll
  for(int k2=0;k2<8;k2++) l_r[k2]=0.f;

  // D staging registers: 8 x float4 (dense 1KB bursts) — ALL 64 lanes active
  float4_t gl[4][2];
  float mi[4][2];
  short8 kf[4], vf[4];

  // dense staging loads: instr (row,half) covers 1KB contiguous
#define LOAD_GL(ts) do{ \
    _Pragma("unroll") \
    for(int row=0; row<4; row++){ \
      const float* rb = Dm + ((size_t)(i0+4*w+row)*NN + (size_t)(ts)*32)*16; \
      gl[row][0] = *(const float4_t*)(rb + l*4); \
      gl[row][1] = *(const float4_t*)(rb + 256 + l*4); \
    } }while(0)

  // convert gl (f32) -> bf16 and store into Dlds[bufb] (wave-private rows).
  // Ends with a compiler memory fence: the ULL stores type-pun the short array;
  // don't let later short8 reads of Dlds be hoisted above them.
#define CVT_STORE(bufb) do{ \
    short* dbp = Dlds + (bufb)*16384; \
    const int jw = (l>>2), r0 = 4*(l&3); \
    _Pragma("unroll") \
    for(int row=0; row<4; row++){ \
      _Pragma("unroll") \
      for(int half=0; half<2; half++){ \
        unsigned u0,u1; float4_t v = gl[row][half]; \
        asm("v_cvt_pk_bf16_f32 %0, %1, %2" : "=v"(u0) : "v"(v[0]), "v"(v[1])); \
        asm("v_cvt_pk_bf16_f32 %0, %1, %2" : "=v"(u1) : "v"(v[2]), "v"(v[3])); \
        unsigned long long pk = (unsigned long long)u0 | ((unsigned long long)u1<<32); \
        *(unsigned long long*)(dbp + (4*w+row)*512 + (half*16+jw)*16 + r0) = pk; \
      } } \
    asm volatile("" ::: "memory"); \
  }while(0)

#define LOAD_MI(tt) do{ \
    size_t jj = (size_t)(tt)*32 + i16; \
    mi[0][0] = mask[(size_t)(i0+4*w+0)*NN + jj] * msc; \
    mi[0][1] = mask[(size_t)(i0+4*w+0)*NN + jj + 16] * msc; \
    mi[1][0] = mask[(size_t)(i0+4*w+1)*NN + jj] * msc; \
    mi[1][1] = mask[(size_t)(i0+4*w+1)*NN + jj + 16] * msc; \
    mi[2][0] = mask[(size_t)(i0+4*w+2)*NN + jj] * msc; \
    mi[2][1] = mask[(size_t)(i0+4*w+2)*NN + jj + 16] * msc; \
    mi[3][0] = mask[(size_t)(i0+4*w+3)*NN + jj] * msc; \
    mi[3][1] = mask[(size_t)(i0+4*w+3)*NN + jj + 16] * msc; }while(0)

#define LOAD_K(tt) do{ \
    const short* kp = Kp + (((size_t)w*256 + (size_t)(tt)*2)*2)*512 + (size_t)l*8; \
    kf[0] = *(const short8*)(kp);        kf[1] = *(const short8*)(kp+512); \
    kf[2] = *(const short8*)(kp+1024);   kf[3] = *(const short8*)(kp+1536); }while(0)

#define LOAD_V(tt) do{ \
    const short* vp = Vp + (((size_t)w*128 + (size_t)(tt))*4)*512 + (size_t)l*8; \
    vf[0] = *(const short8*)(vp);        vf[1] = *(const short8*)(vp+512); \
    vf[2] = *(const short8*)(vp+1024);   vf[3] = *(const short8*)(vp+1536); }while(0)

  const int t0 = jh*64;
  // prologue: stage D(t0) into buf0 (one-time immediate wait), start D(t0+1)
  LOAD_GL(t0);
  LOAD_MI(t0); LOAD_K(t0); LOAD_V(t0);
  CVT_STORE(0);
  LOAD_GL(t0+1);

  for(int t=0; t<64; t++){
    const int cur = t & 1;
    const int tn = (t<63) ? t0+t+1 : t0+63;
    const int tp = (t<62) ? t0+t+2 : t0+63;
    // ---- producer: B-frags from Dlds[cur], RD for rows 4w..4w+3, heads = MFMA M ----
    const short* dcur = Dlds + cur*16384;
    short8 zf;
    #pragma unroll
    for(int e=0;e<8;e++) zf[e] = 0;
    #pragma unroll
    for(int row=0; row<4; row++){
      short8 db0 = zf, db1 = zf;
      if(g < 2){
        db0 = *(const short8*)(dcur + (4*w+row)*512 + i16*16      + 8*g);
        db1 = *(const short8*)(dcur + (4*w+row)*512 + (16+i16)*16 + 8*g);
      }
      float4_t c0 = {mi[row][0],mi[row][0],mi[row][0],mi[row][0]};
      float4_t c1 = {mi[row][1],mi[row][1],mi[row][1],mi[row][1]};
      c0 = MFMA(ra[row], db0, c0,0,0,0);
      c1 = MFMA(ra[row], db1, c1,0,0,0);
      if(g < 2){
        int ib = 4*w + row;
        #pragma unroll
        for(int r=0; r<4; r++){
          rdl[RDS2(cur*8 + 4*g+r, i16,    ib)] = f2bf(c0[r]);
          rdl[RDS2(cur*8 + 4*g+r, 16+i16, ib)] = f2bf(c1[r]);
        }
      }
    }
    // ---- stage D(t+1) into other buffer; issue D(t+2) dense bursts ----
    CVT_STORE(cur^1);
    LOAD_GL(tp);
    BAR();
    // ---- consumer: head w, 32 rows x 32 j (kf/mi of tile t consumed HERE) ----
    float4_t s[2][2];
    s[0][0] = MFMA(qa[0], kf[0], z4,0,0,0); s[0][0] = MFMA(qa[1], kf[1], s[0][0],0,0,0);
    s[0][1] = MFMA(qa[0], kf[2], z4,0,0,0); s[0][1] = MFMA(qa[1], kf[3], s[0][1],0,0,0);
    s[1][0] = MFMA(qa[2], kf[0], z4,0,0,0); s[1][0] = MFMA(qa[3], kf[1], s[1][0],0,0,0);
    s[1][1] = MFMA(qa[2], kf[2], z4,0,0,0); s[1][1] = MFMA(qa[3], kf[3], s[1][1],0,0,0);
    // NOW safe to prefetch next tile's mask/K (kf consumed by the MFMAs above)
    LOAD_MI(tn); LOAD_K(tn);
    float p[2][2][4];
    #pragma unroll
    for(int rg=0; rg<2; rg++){
      #pragma unroll
      for(int jg=0; jg<2; jg++){
        unsigned long long rv = *(const unsigned long long*)&rdl[RDS2(cur*8 + w, jg*16+i16, rg*16+4*g)];
        unsigned lo = (unsigned)rv, hi = (unsigned)(rv>>32);
        float rf0 = bitsf(lo<<16), rf1 = bitsf(lo & 0xffff0000u);
        float rf2 = bitsf(hi<<16), rf3 = bitsf(hi & 0xffff0000u);
        p[rg][jg][0] = __expf((s[rg][jg][0] + rf0)*iscale);
        p[rg][jg][1] = __expf((s[rg][jg][1] + rf1)*iscale);
        p[rg][jg][2] = __expf((s[rg][jg][2] + rf2)*iscale);
        p[rg][jg][3] = __expf((s[rg][jg][3] + rf3)*iscale);
      }
      #pragma unroll
      for(int r=0; r<4; r++) l_r[rg*4+r] += p[rg][0][r] + p[rg][1][r];
    }
    #pragma unroll
    for(int rg=0; rg<2; rg++)
      #pragma unroll
      for(int jg=0; jg<2; jg++)
        #pragma unroll
        for(int r=0; r<4; r++)
          p_lds[PS(w, rg*16 + 4*g + r, jg*16 + i16)] = f2bf(p[rg][jg][r]);
    #pragma unroll
    for(int rg=0; rg<2; rg++){
      short8 pb = *(const short8*)&p_lds[PS(w, rg*16 + i16, 8*g)];
      O[0][rg] = MFMA(vf[0], pb, O[0][rg],0,0,0);
      O[1][rg] = MFMA(vf[1], pb, O[1][rg],0,0,0);
      O[2][rg] = MFMA(vf[2], pb, O[2][rg],0,0,0);
      O[3][rg] = MFMA(vf[3], pb, O[3][rg],0,0,0);
    }
    LOAD_V(tn);
  }
  // final: reduce l over the 16 j-lanes, store partials
  #pragma unroll
  for(int dd=1; dd<16; dd<<=1)
    #pragma unroll
    for(int k2=0; k2<8; k2++) l_r[k2] += __shfl_xor(l_r[k2], dd);
  if(i16 == 0){
    #pragma unroll
    for(int rg=0; rg<2; rg++)
      #pragma unroll
      for(int r=0; r<4; r++)
        lpart[((size_t)jh*8 + w)*NN + i0 + rg*16 + 4*g + r] = l_r[rg*4+r];
  }
  #pragma unroll
  for(int rg=0; rg<2; rg++)
    #pragma unroll
    for(int db=0; db<4; db++)
      *(float4_t*)(Opart + ((size_t)jh*NN + i0 + rg*16 + i16)*512 + w*64 + db*16 + 4*g) = O[db][rg];
}

// ---------------- merge the two j-half partials -> ctx bf16 ----------------
__global__ void k_merge(const float* __restrict__ Op, const float* __restrict__ lp,
                        short* __restrict__ ctx){
  int T = blockIdx.x*256 + threadIdx.x;   // 4096*64 threads, 8 cols each
  int i = T >> 6; int c = (T & 63) * 8;
  int h = c >> 6;
  float lA = lp[(size_t)h*NN + i], lB = lp[(size_t)(8+h)*NN + i];
  float inv = 1.0f / (lA + lB);
  const float4_t* a = (const float4_t*)(Op + (size_t)i*512 + c);
  const float4_t* b = (const float4_t*)(Op + ((size_t)NN + i)*512 + c);
  float4_t x0 = a[0], x1 = a[1], y0 = b[0], y1 = b[1];
  short8 o;
  #pragma unroll
  for(int e=0; e<4; e++){
    o[e]   = f2bf((x0[e]+y0[e])*inv);
    o[e+4] = f2bf((x1[e]+y1[e])*inv);
  }
  *(short8*)(ctx + (size_t)i*512 + c) = o;
}

extern "C" void kernel_launch(void* const* d_in, const int* in_sizes, int n_in,
                              void* d_out, int out_size, void* d_ws, size_t ws_size,
                              hipStream_t stream) {
  (void)in_sizes; (void)n_in; (void)out_size; (void)ws_size;
  const float* H    = (const float*)d_in[0];
  const float* Dm   = (const float*)d_in[1];
  const float* mask = (const float*)d_in[2];
  const float* W    = (const float*)d_in[3];
  const float* Wout = (const float*)d_in[4];
  float* out = (float*)d_out;

  char* ws = (char*)d_ws;
  size_t off = 0;
  auto carve = [&](size_t bytes)->char*{
    char* p = ws + off; off += (bytes + 255) & ~(size_t)255; return p;
  };
  short* Hb    = (short*)carve((size_t)4096*512*2);
  short* Wt    = (short*)carve((size_t)1664*512*2);
  short* Wot   = (short*)carve((size_t)512*512*2);
  short* H2b   = (short*)carve((size_t)4096*1664*2);   // projection output, bf16
  short* Qp    = (short*)carve((size_t)8*256*2*64*8*2);
  short* Kp    = (short*)carve((size_t)8*256*2*64*8*2);
  short* Vp    = (short*)carve((size_t)8*128*4*64*8*2);
  short* Rp    = (short*)carve((size_t)4096*256*2);
  short* ctxb  = (short*)carve((size_t)4096*512*2);
  float* Opart = (float*)carve((size_t)2*4096*512*4);
  float* lp    = (float*)carve((size_t)2*8*4096*4);

  // 1) convert H to bf16; transpose+convert W, Wout
  k_cvt<<<2048, 256, 0, stream>>>(H, Hb, 4096*512/4);
  k_trans<<<dim3(52,16), dim3(32,8), 0, stream>>>(W, Wt, 512, 1664);
  k_trans<<<dim3(16,16), dim3(32,8), 0, stream>>>(Wout, Wot, 512, 512);
  // 2) projection GEMM: H2b = bf16(Hb @ Wt^T)  (4096 x 1664, K=512)
  k_gemm_t<1><<<dim3(64,26), 256, 0, stream>>>(Hb, Wt, H2b, 4096, 1664, 512);
  // 3) pack Q/K/V/R fragment layouts (pure bf16 re-layout)
  k_pack<<<3584, 256, 0, stream>>>(H2b, Qp, Kp, Vp, Rp);
  // 4) fused attention with relative bias D (LDS-staged D, dense bursts)
  k_attn<<<256, 512, 0, stream>>>(Dm, mask, Qp, Kp, Vp, Rp, Opart, lp);
  // 5) merge partials -> ctx bf16
  k_merge<<<1024, 256, 0, stream>>>(Opart, lp, ctxb);
  // 6) output GEMM: out = ctx @ Wout  (4096 x 512, K=512)
  k_gemm_t<0><<<dim3(64,8), 256, 0, stream>>>(ctxb, Wot, out, 4096, 512, 512);
}